// Round 8
// baseline (507.305 us; speedup 1.0000x reference)
//
#include <hip/hip_runtime.h>
#include <hip/hip_bf16.h>

#define NN 100000
#define NE 1600000
#define HID 128
#define NG 64
#define BN_EPS 1e-5f
#define NBUCK 391      // buckets of 256 nodes (dst>>8)
#define BCAP 8192      // fixed slot capacity per bucket (expected ~4092)
#define EPB 8192       // edges per pair_scatter block
#define NSB 196        // ceil(NE/EPB)
#define SBANK 32       // stats spread banks (atomic contention fix)
#define BIGROWS 65536  // rows covered by the 64-row/1024-block stage (1 exact round @ 4 blk/CU)

typedef __attribute__((ext_vector_type(8))) short short8;
typedef __attribute__((ext_vector_type(4))) float floatx4;

__device__ inline unsigned short f2bf_bits(float v) {
    __hip_bfloat16 h = __float2bfloat16(v);
    unsigned short u;
    __builtin_memcpy(&u, &h, 2);
    return u;
}
__device__ inline float4 bf4_to_f4(ushort4 u) {
    float4 f;
    f.x = __uint_as_float((unsigned)u.x << 16);
    f.y = __uint_as_float((unsigned)u.y << 16);
    f.z = __uint_as_float((unsigned)u.z << 16);
    f.w = __uint_as_float((unsigned)u.w << 16);
    return f;
}
__device__ inline void acc8(float* acc, uint4 u) {
    acc[0] += __uint_as_float(u.x << 16); acc[1] += __uint_as_float(u.x & 0xffff0000u);
    acc[2] += __uint_as_float(u.y << 16); acc[3] += __uint_as_float(u.y & 0xffff0000u);
    acc[4] += __uint_as_float(u.z << 16); acc[5] += __uint_as_float(u.z & 0xffff0000u);
    acc[6] += __uint_as_float(u.w << 16); acc[7] += __uint_as_float(u.w & 0xffff0000u);
}

// ---------------- bucketed CSR build ----------------
__global__ __launch_bounds__(1024) void pair_scatter(const int* __restrict__ src, const int* __restrict__ dst,
                                                     int* __restrict__ bcursor, int* __restrict__ pairs) {
    __shared__ int h[NBUCK];
    __shared__ int base[NBUCK];
    __shared__ int cur[NBUCK];
    for (int i = threadIdx.x; i < NBUCK; i += 1024) h[i] = 0;
    __syncthreads();
    int e0 = blockIdx.x * EPB;
    int myd[8], mys[8];
#pragma unroll
    for (int it = 0; it < 8; ++it) {
        int e = e0 + it * 1024 + threadIdx.x;
        if (e < NE) {
            myd[it] = dst[e];
            mys[it] = src[e];
            atomicAdd(&h[myd[it] >> 8], 1);
        } else myd[it] = -1;
    }
    __syncthreads();
    for (int i = threadIdx.x; i < NBUCK; i += 1024) {
        int res = h[i] ? atomicAdd(&bcursor[i], h[i]) : 0;
        base[i] = res;
        cur[i] = 0;
    }
    __syncthreads();
#pragma unroll
    for (int it = 0; it < 8; ++it) {
        if (myd[it] >= 0) {
            int b = myd[it] >> 8;
            int off = base[b] + atomicAdd(&cur[b], 1);
            if (off < BCAP)
                pairs[b * BCAP + off] = (mys[it] << 8) | (myd[it] & 255);
        }
    }
}

__global__ __launch_bounds__(512) void bucket_scan(int* __restrict__ bcursor, int* __restrict__ ebase,
                                                   int* __restrict__ rowptr) {
    __shared__ int s[512];
    int t = threadIdx.x;
    int v = (t < NBUCK) ? min(bcursor[t], BCAP) : 0;
    if (t < NBUCK) bcursor[t] = v;
    s[t] = v;
    __syncthreads();
    for (int off = 1; off < 512; off <<= 1) {
        int x = (t >= off) ? s[t - off] : 0;
        __syncthreads();
        s[t] += x;
        __syncthreads();
    }
    if (t < NBUCK) ebase[t] = s[t] - v;
    if (t == NBUCK - 1) rowptr[NN] = s[t];
}

__global__ __launch_bounds__(256) void bucket_build(const int* __restrict__ pairs, const int* __restrict__ bcursor,
                                                    const int* __restrict__ ebase,
                                                    int* __restrict__ rowptr, int* __restrict__ col) {
    __shared__ int deg[256];
    __shared__ int s[256];
    __shared__ int cur[256];
    int b = blockIdx.x, t = threadIdx.x;
    int cnt = bcursor[b];
    int pbase = b * BCAP;
    deg[t] = 0;
    __syncthreads();
    for (int p = t; p < cnt; p += 256)
        atomicAdd(&deg[pairs[pbase + p] & 255], 1);
    __syncthreads();
    int v = deg[t];
    s[t] = v;
    __syncthreads();
    for (int off = 1; off < 256; off <<= 1) {
        int x = (t >= off) ? s[t - off] : 0;
        __syncthreads();
        s[t] += x;
        __syncthreads();
    }
    int excl = ebase[b] + s[t] - v;
    int node = b * 256 + t;
    if (node < NN) rowptr[node] = excl;
    cur[t] = excl;
    __syncthreads();
    for (int p = t; p < cnt; p += 256) {
        int pk = pairs[pbase + p];
        int pos = atomicAdd(&cur[pk & 255], 1);
        col[pos] = pk >> 8;
    }
}

// ---------------- fp32 -> bf16 row conversion (for x) ----------------
__global__ __launch_bounds__(256) void f2bf(const float* __restrict__ X, unsigned short* __restrict__ O) {
    int i = blockIdx.x * 256 + threadIdx.x;
    if (i >= NN * 16) return;
    const float4* X4 = (const float4*)X;
    float4 a = X4[2 * i], b = X4[2 * i + 1];
    ((ushort4*)O)[2 * i] = make_ushort4(f2bf_bits(a.x), f2bf_bits(a.y), f2bf_bits(a.z), f2bf_bits(a.w));
    ((ushort4*)O)[2 * i + 1] = make_ushort4(f2bf_bits(b.x), f2bf_bits(b.y), f2bf_bits(b.z), f2bf_bits(b.w));
}

// ---------------- W pre-pack (both weights in one launch) ----------------
__global__ __launch_bounds__(512) void pack_w2(const float* __restrict__ W1, const float* __restrict__ W2,
                                               unsigned short* __restrict__ Wp) {
    int t = blockIdx.x;                 // 0..7
    int layer = blockIdx.y;             // 0..2
    int which = threadIdx.x >> 8;       // 0: W1, 1: W2
    int s = (threadIdx.x >> 6) & 3;
    int lane = threadIdx.x & 63;
    int n = t * 16 + (lane & 15);
    int k0 = s * 32 + (lane >> 4) * 8;
    const float* Ws = (which ? W2 : W1) + (size_t)layer * HID * HID;
    unsigned short* dst = Wp + (size_t)(2 * layer + which) * 16384;
    size_t base = (size_t)((t * 4 + s) * 64 + lane) * 8;
#pragma unroll
    for (int j = 0; j < 8; ++j) dst[base + j] = f2bf_bits(Ws[(k0 + j) * 128 + n]);
}

// ---------------- fused per-layer: gather + MLP (templated tile: 64x512 / 32x256) ----------------
// Two-stage schedule kills the 2-round quantization: stage A = 1024 blocks x 64 rows (exactly
// one round at 4 blocks/CU), stage B = 1077 blocks x 32 rows (256 thr, 8 blocks/CU, one round).
#define Z1P 136
template<int ROWS, int NTHR>
__global__ __launch_bounds__(NTHR) void mlp_t(const unsigned short* __restrict__ hb,
        const int* __restrict__ rowptr, const int* __restrict__ col, int rowBase,
        const unsigned short* __restrict__ W1p, const float* __restrict__ b1v,
        const unsigned short* __restrict__ W2p, const float* __restrict__ b2v,
        unsigned short* __restrict__ Zb, float* __restrict__ statsP) {
    constexpr int GRP = NTHR / 16;          // gather groups (16 lanes each)
    constexpr int HH = ROWS / GRP;          // sequential rows per gather group (=2 both shapes)
    __shared__ unsigned short Z1h[ROWS * Z1P];
    __shared__ unsigned short Z1l[ROWS * Z1P];
    __shared__ float cs[256];
    int tid = threadIdx.x;
    if (tid < 256) cs[tid] = 0.f;
    int row0 = rowBase + blockIdx.x * ROWS;

    // ---- phase 0: gather into Z1h/Z1l (A hi/lo) ----
    {
        int g = tid >> 4, l = tid & 15;
        const uint4* h8 = (const uint4*)hb;
#pragma unroll
        for (int hh = 0; hh < HH; ++hh) {
            int lrow = hh * GRP + g;
            int node = row0 + lrow;
            float acc[8];
#pragma unroll
            for (int jj = 0; jj < 8; ++jj) acc[jj] = 0.f;
            if (node < NN) {
                acc8(acc, h8[(size_t)node * 16 + l]);   // self term
                int s = rowptr[node], e = rowptr[node + 1];
                int j = s;
                for (; j + 7 < e; j += 8) {
                    int c0 = col[j], c1 = col[j + 1], c2 = col[j + 2], c3 = col[j + 3];
                    int c4 = col[j + 4], c5 = col[j + 5], c6 = col[j + 6], c7 = col[j + 7];
                    uint4 u0 = h8[(size_t)c0 * 16 + l];
                    uint4 u1 = h8[(size_t)c1 * 16 + l];
                    uint4 u2 = h8[(size_t)c2 * 16 + l];
                    uint4 u3 = h8[(size_t)c3 * 16 + l];
                    uint4 u4 = h8[(size_t)c4 * 16 + l];
                    uint4 u5 = h8[(size_t)c5 * 16 + l];
                    uint4 u6 = h8[(size_t)c6 * 16 + l];
                    uint4 u7 = h8[(size_t)c7 * 16 + l];
                    acc8(acc, u0); acc8(acc, u1); acc8(acc, u2); acc8(acc, u3);
                    acc8(acc, u4); acc8(acc, u5); acc8(acc, u6); acc8(acc, u7);
                }
                for (; j + 3 < e; j += 4) {
                    int c0 = col[j], c1 = col[j + 1], c2 = col[j + 2], c3 = col[j + 3];
                    uint4 u0 = h8[(size_t)c0 * 16 + l];
                    uint4 u1 = h8[(size_t)c1 * 16 + l];
                    uint4 u2 = h8[(size_t)c2 * 16 + l];
                    uint4 u3 = h8[(size_t)c3 * 16 + l];
                    acc8(acc, u0); acc8(acc, u1); acc8(acc, u2); acc8(acc, u3);
                }
                for (; j < e; ++j)
                    acc8(acc, h8[(size_t)col[j] * 16 + l]);
            }
            short8 hi, lo;
#pragma unroll
            for (int jj = 0; jj < 8; ++jj) {
                unsigned short h = f2bf_bits(acc[jj]);
                float hf = __uint_as_float((unsigned)h << 16);
                hi[jj] = (short)h;
                lo[jj] = (short)f2bf_bits(acc[jj] - hf);
            }
            *(short8*)&Z1h[lrow * Z1P + l * 8] = hi;
            *(short8*)&Z1l[lrow * Z1P + l * 8] = lo;
        }
    }
    __syncthreads();

    int lane = tid & 63, wave = tid >> 6;
    int strip = wave >> 1, half = wave & 1;
    int m = lane & 15, quad = lane >> 4;
    const short8* W1f = (const short8*)W1p;
    const short8* W2f = (const short8*)W2p;

    floatx4 acc1[4];
#pragma unroll
    for (int t = 0; t < 4; ++t) acc1[t] = (floatx4){0.f, 0.f, 0.f, 0.f};
#pragma unroll
    for (int s = 0; s < 4; ++s) {
        short8 bh[4];
#pragma unroll
        for (int tt = 0; tt < 4; ++tt) bh[tt] = W1f[((half * 4 + tt) * 4 + s) * 64 + lane];
        short8 ah = *(short8*)&Z1h[(strip * 16 + m) * Z1P + s * 32 + quad * 8];
        short8 al = *(short8*)&Z1l[(strip * 16 + m) * Z1P + s * 32 + quad * 8];
#pragma unroll
        for (int tt = 0; tt < 4; ++tt) {
            acc1[tt] = __builtin_amdgcn_mfma_f32_16x16x32_bf16(ah, bh[tt], acc1[tt], 0, 0, 0);
            acc1[tt] = __builtin_amdgcn_mfma_f32_16x16x32_bf16(al, bh[tt], acc1[tt], 0, 0, 0);
        }
    }
    __syncthreads();   // A fully consumed before Z1 overwrite
#pragma unroll
    for (int tt = 0; tt < 4; ++tt) {
        int colc = (half * 4 + tt) * 16 + m;
        float bv = b1v[colc];
#pragma unroll
        for (int rr = 0; rr < 4; ++rr) {
            int lrow = strip * 16 + quad * 4 + rr;
            float o = fmaxf(acc1[tt][rr] + bv, 0.f);
            unsigned short hi = f2bf_bits(o);
            float hf = __uint_as_float((unsigned)hi << 16);
            Z1h[lrow * Z1P + colc] = hi;
            Z1l[lrow * Z1P + colc] = f2bf_bits(o - hf);
        }
    }
    __syncthreads();

    floatx4 acc2[4];
#pragma unroll
    for (int t = 0; t < 4; ++t) acc2[t] = (floatx4){0.f, 0.f, 0.f, 0.f};
#pragma unroll
    for (int s = 0; s < 4; ++s) {
        short8 bh[4];
#pragma unroll
        for (int tt = 0; tt < 4; ++tt) bh[tt] = W2f[((half * 4 + tt) * 4 + s) * 64 + lane];
        short8 ah = *(short8*)&Z1h[(strip * 16 + m) * Z1P + s * 32 + quad * 8];
        short8 al = *(short8*)&Z1l[(strip * 16 + m) * Z1P + s * 32 + quad * 8];
#pragma unroll
        for (int tt = 0; tt < 4; ++tt) {
            acc2[tt] = __builtin_amdgcn_mfma_f32_16x16x32_bf16(ah, bh[tt], acc2[tt], 0, 0, 0);
            acc2[tt] = __builtin_amdgcn_mfma_f32_16x16x32_bf16(al, bh[tt], acc2[tt], 0, 0, 0);
        }
    }
    // epilogue: z2 bf16 store + column stats
#pragma unroll
    for (int tt = 0; tt < 4; ++tt) {
        int colc = (half * 4 + tt) * 16 + m;
        float bv = b2v[colc];
        float csum = 0.f, csq = 0.f;
#pragma unroll
        for (int rr = 0; rr < 4; ++rr) {
            int grow = row0 + strip * 16 + quad * 4 + rr;
            if (grow < NN) {
                float o = acc2[tt][rr] + bv;
                Zb[(size_t)grow * HID + colc] = f2bf_bits(o);
                csum += o; csq += o * o;
            }
        }
        csum += __shfl_xor(csum, 16); csum += __shfl_xor(csum, 32);
        csq  += __shfl_xor(csq, 16);  csq  += __shfl_xor(csq, 32);
        if (quad == 0) {
            atomicAdd(&cs[colc], csum);
            atomicAdd(&cs[128 + colc], csq);
        }
    }
    __syncthreads();
    if (tid < 256) {
        float* sp = statsP + ((blockIdx.x & (SBANK - 1)) << 8);
        atomicAdd(&sp[tid], cs[tid]);
    }
}

// ---------------- BN finalize ----------------
__global__ void bn_fin(const float* __restrict__ statsP, const float* __restrict__ gamma,
                       const float* __restrict__ beta, float* __restrict__ ss) {
    int c = threadIdx.x;
    float s = 0.f, q = 0.f;
    for (int b = 0; b < SBANK; ++b) {
        s += statsP[b * 256 + c];
        q += statsP[b * 256 + 128 + c];
    }
    float mu = s * (1.f / NN);
    float var = q * (1.f / NN) - mu * mu;
    float sc = gamma[c] * rsqrtf(var + BN_EPS);
    ss[c] = sc;
    ss[128 + c] = beta[c] - mu * sc;
}

// ---------------- BN+ReLU in-place on bf16 z2 ----------------
__global__ __launch_bounds__(256) void bn_relu_bf(unsigned short* __restrict__ Zb,
                                                  const float* __restrict__ ss) {
    int i = blockIdx.x * 256 + threadIdx.x;
    if (i >= NN * 16) return;
    int g = i & 15;
    const float4* S4 = (const float4*)ss;
    float4 sc0 = S4[g * 2], sc1 = S4[g * 2 + 1];
    float4 sh0 = S4[32 + g * 2], sh1 = S4[32 + g * 2 + 1];
    ushort4 u0 = ((ushort4*)Zb)[2 * i], u1 = ((ushort4*)Zb)[2 * i + 1];
    float4 a = bf4_to_f4(u0), b = bf4_to_f4(u1);
    a.x = fmaxf(fmaf(a.x, sc0.x, sh0.x), 0.f); a.y = fmaxf(fmaf(a.y, sc0.y, sh0.y), 0.f);
    a.z = fmaxf(fmaf(a.z, sc0.z, sh0.z), 0.f); a.w = fmaxf(fmaf(a.w, sc0.w, sh0.w), 0.f);
    b.x = fmaxf(fmaf(b.x, sc1.x, sh1.x), 0.f); b.y = fmaxf(fmaf(b.y, sc1.y, sh1.y), 0.f);
    b.z = fmaxf(fmaf(b.z, sc1.z, sh1.z), 0.f); b.w = fmaxf(fmaf(b.w, sc1.w, sh1.w), 0.f);
    ((ushort4*)Zb)[2 * i] = make_ushort4(f2bf_bits(a.x), f2bf_bits(a.y), f2bf_bits(a.z), f2bf_bits(a.w));
    ((ushort4*)Zb)[2 * i + 1] = make_ushort4(f2bf_bits(b.x), f2bf_bits(b.y), f2bf_bits(b.z), f2bf_bits(b.w));
}

// ---------------- fused final BN+ReLU + mean-pool partial (3125 blocks, reg bins) ----------------
__global__ __launch_bounds__(256) void bn_pool(const unsigned short* __restrict__ Zb,
                                               const float* __restrict__ ss,
                                               const int* __restrict__ batch,
                                               float* __restrict__ out, float* __restrict__ gsum) {
    __shared__ float accG[2][128];
    __shared__ int g0s;
    int t = threadIdx.x;
    if (t < 128) accG[1][t] = 0.f; else accG[0][t - 128] = 0.f;
    if (t < 128) accG[0][t] = 0.f;
    int n0 = blockIdx.x * 32;
    if (t == 0) g0s = batch[n0];
    __syncthreads();
    int g0 = g0s;
    int sub = t & 31, r = t >> 5;
    const float4* S4 = (const float4*)ss;
    float4 sc = S4[sub], sh = S4[32 + sub];
    float4 r0 = make_float4(0.f, 0.f, 0.f, 0.f);
    float4 r1 = make_float4(0.f, 0.f, 0.f, 0.f);
#pragma unroll
    for (int it = 0; it < 4; ++it) {
        int node = n0 + it * 8 + r;
        float4 v = bf4_to_f4(((const ushort4*)Zb)[(size_t)node * 32 + sub]);
        v.x = fmaxf(fmaf(v.x, sc.x, sh.x), 0.f);
        v.y = fmaxf(fmaf(v.y, sc.y, sh.y), 0.f);
        v.z = fmaxf(fmaf(v.z, sc.z, sh.z), 0.f);
        v.w = fmaxf(fmaf(v.w, sc.w, sh.w), 0.f);
        ((float4*)out)[(size_t)node * 32 + sub] = v;
        int gi = batch[node] - g0;
        if (gi == 0) {
            r0.x += v.x; r0.y += v.y; r0.z += v.z; r0.w += v.w;
        } else if (gi == 1) {
            r1.x += v.x; r1.y += v.y; r1.z += v.z; r1.w += v.w;
        } else {
            atomicAdd(&gsum[(size_t)(g0 + gi) * HID + sub * 4 + 0], v.x);
            atomicAdd(&gsum[(size_t)(g0 + gi) * HID + sub * 4 + 1], v.y);
            atomicAdd(&gsum[(size_t)(g0 + gi) * HID + sub * 4 + 2], v.z);
            atomicAdd(&gsum[(size_t)(g0 + gi) * HID + sub * 4 + 3], v.w);
        }
    }
    if (r0.x != 0.f || r0.y != 0.f || r0.z != 0.f || r0.w != 0.f) {
        atomicAdd(&accG[0][sub * 4 + 0], r0.x);
        atomicAdd(&accG[0][sub * 4 + 1], r0.y);
        atomicAdd(&accG[0][sub * 4 + 2], r0.z);
        atomicAdd(&accG[0][sub * 4 + 3], r0.w);
    }
    if (r1.x != 0.f || r1.y != 0.f || r1.z != 0.f || r1.w != 0.f) {
        atomicAdd(&accG[1][sub * 4 + 0], r1.x);
        atomicAdd(&accG[1][sub * 4 + 1], r1.y);
        atomicAdd(&accG[1][sub * 4 + 2], r1.z);
        atomicAdd(&accG[1][sub * 4 + 3], r1.w);
    }
    __syncthreads();
    {
        int gi = t >> 7, c = t & 127;
        float v = accG[gi][c];
        if (v != 0.f && g0 + gi < NG) atomicAdd(&gsum[(g0 + gi) * HID + c], v);
    }
}

// ---------------- pool finalize (binary-search counts inline) ----------------
__global__ void pool_final(const int* __restrict__ batch, const float* __restrict__ gsum,
                           float* __restrict__ outG) {
    int g = blockIdx.x, t = threadIdx.x;
    int lo = 0, hi = NN;
    while (lo < hi) { int mid = (lo + hi) >> 1; if (batch[mid] < g) lo = mid + 1; else hi = mid; }
    int s = lo;
    int g1 = g + 1;
    lo = 0; hi = NN;
    while (lo < hi) { int mid = (lo + hi) >> 1; if (batch[mid] < g1) lo = mid + 1; else hi = mid; }
    float cnt = fmaxf((float)(lo - s), 1.f);
    outG[g * HID + t] = gsum[g * HID + t] / cnt;
}

extern "C" void kernel_launch(void* const* d_in, const int* in_sizes, int n_in,
                              void* d_out, int out_size, void* d_ws, size_t ws_size,
                              hipStream_t stream) {
    const float* x = (const float*)d_in[0];
    const int* ei = (const int*)d_in[1];
    const int* batch = (const int*)d_in[2];
    const float* W1 = (const float*)d_in[3];
    const float* b1 = (const float*)d_in[4];
    const float* W2 = (const float*)d_in[5];
    const float* b2 = (const float*)d_in[6];
    const float* gamma = (const float*)d_in[7];
    const float* beta = (const float*)d_in[8];
    float* out = (float*)d_out;
    float* outG = out + (size_t)NN * HID;

    // workspace layout
    unsigned short* H0 = (unsigned short*)d_ws;                    // NN*HID bf16 (ping)
    unsigned short* H1 = H0 + (size_t)NN * HID;                    // NN*HID bf16 (pong)
    unsigned short* PB = H1 + (size_t)NN * HID;                    // 25.6MB scratch (pairs, CSR build only)
    int* col = (int*)(PB + (size_t)NN * HID);                      // NE
    int* rowptr = col + NE;                                        // 100004 reserved
    int* ebase = rowptr + 100004;                                  // 512
    int* bcursor = ebase + 512;                                    // 512 (zero region start)
    float* statsP = (float*)(bcursor + 512);                       // 3 * 32 * 256
    float* gsum = statsP + 3 * SBANK * 256;                        // 8192 (zero region end)
    float* ss = gsum + 8192;                                       // 3 x 256
    unsigned short* Wp = (unsigned short*)(ss + 3 * 256);          // 6 x 16384 ushorts
    int* pairs = (int*)PB;                                         // NBUCK*BCAP ints = 12.8MB <= 25.6MB

    const int* srcv = ei;
    const int* dstv = ei + NE;

    hipMemsetAsync(bcursor, 0, (512 + 3 * SBANK * 256 + 8192) * sizeof(int), stream);

    // bucketed CSR build
    pair_scatter<<<NSB, 1024, 0, stream>>>(srcv, dstv, bcursor, pairs);
    bucket_scan<<<1, 512, 0, stream>>>(bcursor, ebase, rowptr);
    bucket_build<<<NBUCK, 256, 0, stream>>>(pairs, bcursor, ebase, rowptr, col);

    // pack weights; convert x to bf16
    pack_w2<<<dim3(8, 3), 512, 0, stream>>>(W1, W2, Wp);
    f2bf<<<NN * 16 / 256, 256, 0, stream>>>(x, H0);

    const int nBig = BIGROWS / 64;                   // 1024 blocks (one exact round @ 4/CU)
    const int nSmall = (NN - BIGROWS) / 32;          // 1077 blocks (one round @ 8/CU)
    unsigned short* bufs[2] = {H0, H1};
    for (int l = 0; l < 3; ++l) {
        unsigned short* hin = bufs[l & 1];
        unsigned short* hout = bufs[(l + 1) & 1];
        const unsigned short* w1 = Wp + (size_t)(2 * l) * 16384;
        const unsigned short* w2 = Wp + (size_t)(2 * l + 1) * 16384;
        float* sp = statsP + (size_t)l * SBANK * 256;
        mlp_t<64, 512><<<nBig, 512, 0, stream>>>(hin, rowptr, col, 0,
                                                 w1, b1 + l * HID, w2, b2 + l * HID, hout, sp);
        mlp_t<32, 256><<<nSmall, 256, 0, stream>>>(hin, rowptr, col, BIGROWS,
                                                   w1, b1 + l * HID, w2, b2 + l * HID, hout, sp);
        bn_fin<<<1, 128, 0, stream>>>(sp, gamma + l * HID, beta + l * HID, ss + l * 256);
        if (l < 2)
            bn_relu_bf<<<NN * 16 / 256, 256, 0, stream>>>(hout, ss + l * 256);
    }

    // fused final BN+ReLU + pooling (3125 blocks, 32 nodes each)
    bn_pool<<<NN / 32, 256, 0, stream>>>(H1, ss + 2 * 256, batch, out, gsum);
    pool_final<<<NG, 128, 0, stream>>>(batch, gsum, outG);
}

// Round 9
// 463.498 us; speedup vs baseline: 1.0945x; 1.0945x over previous
//
#include <hip/hip_runtime.h>
#include <hip/hip_bf16.h>

#define NN 100000
#define NE 1600000
#define HID 128
#define NG 64
#define BN_EPS 1e-5f
#define NBUCK 391      // buckets of 256 nodes (dst>>8)
#define BCAP 8192      // fixed slot capacity per bucket (expected ~4092)
#define EPB 8192       // edges per pair_scatter block
#define NSB 196        // ceil(NE/EPB)
#define SBANK 32       // stats spread banks (atomic contention fix)

typedef __attribute__((ext_vector_type(8))) short short8;
typedef __attribute__((ext_vector_type(4))) float floatx4;

__device__ inline unsigned short f2bf_bits(float v) {
    __hip_bfloat16 h = __float2bfloat16(v);
    unsigned short u;
    __builtin_memcpy(&u, &h, 2);
    return u;
}
__device__ inline float4 bf4_to_f4(ushort4 u) {
    float4 f;
    f.x = __uint_as_float((unsigned)u.x << 16);
    f.y = __uint_as_float((unsigned)u.y << 16);
    f.z = __uint_as_float((unsigned)u.z << 16);
    f.w = __uint_as_float((unsigned)u.w << 16);
    return f;
}
__device__ inline void acc8(float* acc, uint4 u) {
    acc[0] += __uint_as_float(u.x << 16); acc[1] += __uint_as_float(u.x & 0xffff0000u);
    acc[2] += __uint_as_float(u.y << 16); acc[3] += __uint_as_float(u.y & 0xffff0000u);
    acc[4] += __uint_as_float(u.z << 16); acc[5] += __uint_as_float(u.z & 0xffff0000u);
    acc[6] += __uint_as_float(u.w << 16); acc[7] += __uint_as_float(u.w & 0xffff0000u);
}

// ---------------- bucketed CSR build ----------------
__global__ __launch_bounds__(1024) void pair_scatter(const int* __restrict__ src, const int* __restrict__ dst,
                                                     int* __restrict__ bcursor, int* __restrict__ pairs) {
    __shared__ int h[NBUCK];
    __shared__ int base[NBUCK];
    __shared__ int cur[NBUCK];
    for (int i = threadIdx.x; i < NBUCK; i += 1024) h[i] = 0;
    __syncthreads();
    int e0 = blockIdx.x * EPB;
    int myd[8], mys[8];
#pragma unroll
    for (int it = 0; it < 8; ++it) {
        int e = e0 + it * 1024 + threadIdx.x;
        if (e < NE) {
            myd[it] = dst[e];
            mys[it] = src[e];
            atomicAdd(&h[myd[it] >> 8], 1);
        } else myd[it] = -1;
    }
    __syncthreads();
    for (int i = threadIdx.x; i < NBUCK; i += 1024) {
        int res = h[i] ? atomicAdd(&bcursor[i], h[i]) : 0;
        base[i] = res;
        cur[i] = 0;
    }
    __syncthreads();
#pragma unroll
    for (int it = 0; it < 8; ++it) {
        if (myd[it] >= 0) {
            int b = myd[it] >> 8;
            int off = base[b] + atomicAdd(&cur[b], 1);
            if (off < BCAP)
                pairs[b * BCAP + off] = (mys[it] << 8) | (myd[it] & 255);
        }
    }
}

__global__ __launch_bounds__(512) void bucket_scan(int* __restrict__ bcursor, int* __restrict__ ebase,
                                                   int* __restrict__ rowptr) {
    __shared__ int s[512];
    int t = threadIdx.x;
    int v = (t < NBUCK) ? min(bcursor[t], BCAP) : 0;
    if (t < NBUCK) bcursor[t] = v;
    s[t] = v;
    __syncthreads();
    for (int off = 1; off < 512; off <<= 1) {
        int x = (t >= off) ? s[t - off] : 0;
        __syncthreads();
        s[t] += x;
        __syncthreads();
    }
    if (t < NBUCK) ebase[t] = s[t] - v;
    if (t == NBUCK - 1) rowptr[NN] = s[t];
}

__global__ __launch_bounds__(256) void bucket_build(const int* __restrict__ pairs, const int* __restrict__ bcursor,
                                                    const int* __restrict__ ebase,
                                                    int* __restrict__ rowptr, int* __restrict__ col) {
    __shared__ int deg[256];
    __shared__ int s[256];
    __shared__ int cur[256];
    int b = blockIdx.x, t = threadIdx.x;
    int cnt = bcursor[b];
    int pbase = b * BCAP;
    deg[t] = 0;
    __syncthreads();
    for (int p = t; p < cnt; p += 256)
        atomicAdd(&deg[pairs[pbase + p] & 255], 1);
    __syncthreads();
    int v = deg[t];
    s[t] = v;
    __syncthreads();
    for (int off = 1; off < 256; off <<= 1) {
        int x = (t >= off) ? s[t - off] : 0;
        __syncthreads();
        s[t] += x;
        __syncthreads();
    }
    int excl = ebase[b] + s[t] - v;
    int node = b * 256 + t;
    if (node < NN) rowptr[node] = excl;
    cur[t] = excl;
    __syncthreads();
    for (int p = t; p < cnt; p += 256) {
        int pk = pairs[pbase + p];
        int pos = atomicAdd(&cur[pk & 255], 1);
        col[pos] = pk >> 8;
    }
}

// ---------------- prep: W pre-pack (blocks 0..47) + x fp32->bf16 (rest) ----------------
__global__ __launch_bounds__(256) void prep(const float* __restrict__ X, unsigned short* __restrict__ O,
                                            const float* __restrict__ W1, const float* __restrict__ W2,
                                            unsigned short* __restrict__ Wp) {
    int b = blockIdx.x;
    if (b < 48) {
        int layer = b >> 4;            // 0..2
        int which = (b >> 3) & 1;      // 0: W1, 1: W2
        int t = b & 7;                 // 0..7
        int s = threadIdx.x >> 6;
        int lane = threadIdx.x & 63;
        int n = t * 16 + (lane & 15);
        int k0 = s * 32 + (lane >> 4) * 8;
        const float* Ws = (which ? W2 : W1) + (size_t)layer * HID * HID;
        unsigned short* dst = Wp + (size_t)(2 * layer + which) * 16384;
        size_t base = (size_t)((t * 4 + s) * 64 + lane) * 8;
#pragma unroll
        for (int j = 0; j < 8; ++j) dst[base + j] = f2bf_bits(Ws[(k0 + j) * 128 + n]);
        return;
    }
    int i = (b - 48) * 256 + threadIdx.x;
    if (i >= NN * 16) return;
    const float4* X4 = (const float4*)X;
    float4 a = X4[2 * i], c = X4[2 * i + 1];
    ((ushort4*)O)[2 * i] = make_ushort4(f2bf_bits(a.x), f2bf_bits(a.y), f2bf_bits(a.z), f2bf_bits(a.w));
    ((ushort4*)O)[2 * i + 1] = make_ushort4(f2bf_bits(c.x), f2bf_bits(c.y), f2bf_bits(c.z), f2bf_bits(c.w));
}

// ---------------- fused per-layer: gather + MLP (v5/v10 body; proven 90.6 us, best rate) ----------------
#define Z1P 136
__global__ __launch_bounds__(512) void mlp_v10(const unsigned short* __restrict__ hb,
        const int* __restrict__ rowptr, const int* __restrict__ col,
        const unsigned short* __restrict__ W1p, const float* __restrict__ b1v,
        const unsigned short* __restrict__ W2p, const float* __restrict__ b2v,
        unsigned short* __restrict__ Zb, float* __restrict__ statsP) {
    __shared__ unsigned short Z1h[64 * Z1P];
    __shared__ unsigned short Z1l[64 * Z1P];
    __shared__ float cs[256];
    int tid = threadIdx.x;
    if (tid < 256) cs[tid] = 0.f;
    int row0 = blockIdx.x * 64;

    // ---- phase 0: gather into Z1h/Z1l (A hi/lo) ----
    {
        int g = tid >> 4, l = tid & 15;
        const uint4* h8 = (const uint4*)hb;
#pragma unroll
        for (int hh = 0; hh < 2; ++hh) {
            int lrow = hh * 32 + g;
            int node = row0 + lrow;
            float acc[8];
#pragma unroll
            for (int jj = 0; jj < 8; ++jj) acc[jj] = 0.f;
            if (node < NN) {
                acc8(acc, h8[(size_t)node * 16 + l]);   // self term
                int s = rowptr[node], e = rowptr[node + 1];
                int j = s;
                for (; j + 7 < e; j += 8) {
                    int c0 = col[j], c1 = col[j + 1], c2 = col[j + 2], c3 = col[j + 3];
                    int c4 = col[j + 4], c5 = col[j + 5], c6 = col[j + 6], c7 = col[j + 7];
                    uint4 u0 = h8[(size_t)c0 * 16 + l];
                    uint4 u1 = h8[(size_t)c1 * 16 + l];
                    uint4 u2 = h8[(size_t)c2 * 16 + l];
                    uint4 u3 = h8[(size_t)c3 * 16 + l];
                    uint4 u4 = h8[(size_t)c4 * 16 + l];
                    uint4 u5 = h8[(size_t)c5 * 16 + l];
                    uint4 u6 = h8[(size_t)c6 * 16 + l];
                    uint4 u7 = h8[(size_t)c7 * 16 + l];
                    acc8(acc, u0); acc8(acc, u1); acc8(acc, u2); acc8(acc, u3);
                    acc8(acc, u4); acc8(acc, u5); acc8(acc, u6); acc8(acc, u7);
                }
                for (; j + 3 < e; j += 4) {
                    int c0 = col[j], c1 = col[j + 1], c2 = col[j + 2], c3 = col[j + 3];
                    uint4 u0 = h8[(size_t)c0 * 16 + l];
                    uint4 u1 = h8[(size_t)c1 * 16 + l];
                    uint4 u2 = h8[(size_t)c2 * 16 + l];
                    uint4 u3 = h8[(size_t)c3 * 16 + l];
                    acc8(acc, u0); acc8(acc, u1); acc8(acc, u2); acc8(acc, u3);
                }
                for (; j < e; ++j)
                    acc8(acc, h8[(size_t)col[j] * 16 + l]);
            }
            short8 hi, lo;
#pragma unroll
            for (int jj = 0; jj < 8; ++jj) {
                unsigned short h = f2bf_bits(acc[jj]);
                float hf = __uint_as_float((unsigned)h << 16);
                hi[jj] = (short)h;
                lo[jj] = (short)f2bf_bits(acc[jj] - hf);
            }
            *(short8*)&Z1h[lrow * Z1P + l * 8] = hi;
            *(short8*)&Z1l[lrow * Z1P + l * 8] = lo;
        }
    }
    __syncthreads();

    int lane = tid & 63, wave = tid >> 6;
    int strip = wave >> 1, half = wave & 1;
    int m = lane & 15, quad = lane >> 4;
    const short8* W1f = (const short8*)W1p;
    const short8* W2f = (const short8*)W2p;

    floatx4 acc1[4];
#pragma unroll
    for (int t = 0; t < 4; ++t) acc1[t] = (floatx4){0.f, 0.f, 0.f, 0.f};
#pragma unroll
    for (int s = 0; s < 4; ++s) {
        short8 bh[4];
#pragma unroll
        for (int tt = 0; tt < 4; ++tt) bh[tt] = W1f[((half * 4 + tt) * 4 + s) * 64 + lane];
        short8 ah = *(short8*)&Z1h[(strip * 16 + m) * Z1P + s * 32 + quad * 8];
        short8 al = *(short8*)&Z1l[(strip * 16 + m) * Z1P + s * 32 + quad * 8];
#pragma unroll
        for (int tt = 0; tt < 4; ++tt) {
            acc1[tt] = __builtin_amdgcn_mfma_f32_16x16x32_bf16(ah, bh[tt], acc1[tt], 0, 0, 0);
            acc1[tt] = __builtin_amdgcn_mfma_f32_16x16x32_bf16(al, bh[tt], acc1[tt], 0, 0, 0);
        }
    }
    __syncthreads();   // A fully consumed before Z1 overwrite
#pragma unroll
    for (int tt = 0; tt < 4; ++tt) {
        int colc = (half * 4 + tt) * 16 + m;
        float bv = b1v[colc];
#pragma unroll
        for (int rr = 0; rr < 4; ++rr) {
            int lrow = strip * 16 + quad * 4 + rr;
            float o = fmaxf(acc1[tt][rr] + bv, 0.f);
            unsigned short hi = f2bf_bits(o);
            float hf = __uint_as_float((unsigned)hi << 16);
            Z1h[lrow * Z1P + colc] = hi;
            Z1l[lrow * Z1P + colc] = f2bf_bits(o - hf);
        }
    }
    __syncthreads();

    floatx4 acc2[4];
#pragma unroll
    for (int t = 0; t < 4; ++t) acc2[t] = (floatx4){0.f, 0.f, 0.f, 0.f};
#pragma unroll
    for (int s = 0; s < 4; ++s) {
        short8 bh[4];
#pragma unroll
        for (int tt = 0; tt < 4; ++tt) bh[tt] = W2f[((half * 4 + tt) * 4 + s) * 64 + lane];
        short8 ah = *(short8*)&Z1h[(strip * 16 + m) * Z1P + s * 32 + quad * 8];
        short8 al = *(short8*)&Z1l[(strip * 16 + m) * Z1P + s * 32 + quad * 8];
#pragma unroll
        for (int tt = 0; tt < 4; ++tt) {
            acc2[tt] = __builtin_amdgcn_mfma_f32_16x16x32_bf16(ah, bh[tt], acc2[tt], 0, 0, 0);
            acc2[tt] = __builtin_amdgcn_mfma_f32_16x16x32_bf16(al, bh[tt], acc2[tt], 0, 0, 0);
        }
    }
    // epilogue: z2 bf16 store + column stats
#pragma unroll
    for (int tt = 0; tt < 4; ++tt) {
        int colc = (half * 4 + tt) * 16 + m;
        float bv = b2v[colc];
        float csum = 0.f, csq = 0.f;
#pragma unroll
        for (int rr = 0; rr < 4; ++rr) {
            int grow = row0 + strip * 16 + quad * 4 + rr;
            if (grow < NN) {
                float o = acc2[tt][rr] + bv;
                Zb[(size_t)grow * HID + colc] = f2bf_bits(o);
                csum += o; csq += o * o;
            }
        }
        csum += __shfl_xor(csum, 16); csum += __shfl_xor(csum, 32);
        csq  += __shfl_xor(csq, 16);  csq  += __shfl_xor(csq, 32);
        if (quad == 0) {
            atomicAdd(&cs[colc], csum);
            atomicAdd(&cs[128 + colc], csq);
        }
    }
    __syncthreads();
    if (tid < 256) {
        float* sp = statsP + ((blockIdx.x & (SBANK - 1)) << 8);
        atomicAdd(&sp[tid], cs[tid]);
    }
}

// ---------------- BN+ReLU in-place on bf16 z2 (block-local BN finalize; no bn_fin launch) ----------------
__global__ __launch_bounds__(256) void bn_relu_bf(unsigned short* __restrict__ Zb,
                                                  const float* __restrict__ statsP,
                                                  const float* __restrict__ gamma,
                                                  const float* __restrict__ beta) {
    __shared__ float ssL[256];
    int t = threadIdx.x;
    {
        float s = 0.f;
#pragma unroll 4
        for (int b = 0; b < SBANK; ++b) s += statsP[b * 256 + t];
        ssL[t] = s;
    }
    __syncthreads();
    if (t < 128) {
        float mu = ssL[t] * (1.f / NN);
        float var = ssL[128 + t] * (1.f / NN) - mu * mu;
        float sc = gamma[t] * rsqrtf(var + BN_EPS);
        ssL[t] = sc;
        ssL[128 + t] = beta[t] - mu * sc;
    }
    __syncthreads();
    for (int i = blockIdx.x * 256 + t; i < NN * 16; i += gridDim.x * 256) {
        int g = i & 15;
        float4 sc0 = *(float4*)&ssL[g * 8];
        float4 sc1 = *(float4*)&ssL[g * 8 + 4];
        float4 sh0 = *(float4*)&ssL[128 + g * 8];
        float4 sh1 = *(float4*)&ssL[128 + g * 8 + 4];
        ushort4 u0 = ((ushort4*)Zb)[2 * i], u1 = ((ushort4*)Zb)[2 * i + 1];
        float4 a = bf4_to_f4(u0), b = bf4_to_f4(u1);
        a.x = fmaxf(fmaf(a.x, sc0.x, sh0.x), 0.f); a.y = fmaxf(fmaf(a.y, sc0.y, sh0.y), 0.f);
        a.z = fmaxf(fmaf(a.z, sc0.z, sh0.z), 0.f); a.w = fmaxf(fmaf(a.w, sc0.w, sh0.w), 0.f);
        b.x = fmaxf(fmaf(b.x, sc1.x, sh1.x), 0.f); b.y = fmaxf(fmaf(b.y, sc1.y, sh1.y), 0.f);
        b.z = fmaxf(fmaf(b.z, sc1.z, sh1.z), 0.f); b.w = fmaxf(fmaf(b.w, sc1.w, sh1.w), 0.f);
        ((ushort4*)Zb)[2 * i] = make_ushort4(f2bf_bits(a.x), f2bf_bits(a.y), f2bf_bits(a.z), f2bf_bits(a.w));
        ((ushort4*)Zb)[2 * i + 1] = make_ushort4(f2bf_bits(b.x), f2bf_bits(b.y), f2bf_bits(b.z), f2bf_bits(b.w));
    }
}

// ---------------- fused final BN+ReLU + mean-pool partial (block-local BN finalize) ----------------
__global__ __launch_bounds__(256) void bn_pool(const unsigned short* __restrict__ Zb,
                                               const float* __restrict__ statsP,
                                               const float* __restrict__ gamma,
                                               const float* __restrict__ beta,
                                               const int* __restrict__ batch,
                                               float* __restrict__ out, float* __restrict__ gsum) {
    __shared__ float ssL[256];
    __shared__ float accG[2][128];
    __shared__ int g0s;
    int t = threadIdx.x;
    ((float*)accG)[t] = 0.f;
    {
        float s = 0.f;
#pragma unroll 4
        for (int b = 0; b < SBANK; ++b) s += statsP[b * 256 + t];
        ssL[t] = s;
    }
    int n0 = blockIdx.x * 32;
    if (t == 0) g0s = batch[n0];
    __syncthreads();
    if (t < 128) {
        float mu = ssL[t] * (1.f / NN);
        float var = ssL[128 + t] * (1.f / NN) - mu * mu;
        float sc = gamma[t] * rsqrtf(var + BN_EPS);
        ssL[t] = sc;
        ssL[128 + t] = beta[t] - mu * sc;
    }
    __syncthreads();
    int g0 = g0s;
    int sub = t & 31, r = t >> 5;
    float4 sc = *(float4*)&ssL[sub * 4];
    float4 sh = *(float4*)&ssL[128 + sub * 4];
    float4 r0 = make_float4(0.f, 0.f, 0.f, 0.f);
    float4 r1 = make_float4(0.f, 0.f, 0.f, 0.f);
#pragma unroll
    for (int it = 0; it < 4; ++it) {
        int node = n0 + it * 8 + r;
        float4 v = bf4_to_f4(((const ushort4*)Zb)[(size_t)node * 32 + sub]);
        v.x = fmaxf(fmaf(v.x, sc.x, sh.x), 0.f);
        v.y = fmaxf(fmaf(v.y, sc.y, sh.y), 0.f);
        v.z = fmaxf(fmaf(v.z, sc.z, sh.z), 0.f);
        v.w = fmaxf(fmaf(v.w, sc.w, sh.w), 0.f);
        ((float4*)out)[(size_t)node * 32 + sub] = v;
        int gi = batch[node] - g0;
        if (gi == 0) {
            r0.x += v.x; r0.y += v.y; r0.z += v.z; r0.w += v.w;
        } else if (gi == 1) {
            r1.x += v.x; r1.y += v.y; r1.z += v.z; r1.w += v.w;
        } else {
            atomicAdd(&gsum[(size_t)(g0 + gi) * HID + sub * 4 + 0], v.x);
            atomicAdd(&gsum[(size_t)(g0 + gi) * HID + sub * 4 + 1], v.y);
            atomicAdd(&gsum[(size_t)(g0 + gi) * HID + sub * 4 + 2], v.z);
            atomicAdd(&gsum[(size_t)(g0 + gi) * HID + sub * 4 + 3], v.w);
        }
    }
    if (r0.x != 0.f || r0.y != 0.f || r0.z != 0.f || r0.w != 0.f) {
        atomicAdd(&accG[0][sub * 4 + 0], r0.x);
        atomicAdd(&accG[0][sub * 4 + 1], r0.y);
        atomicAdd(&accG[0][sub * 4 + 2], r0.z);
        atomicAdd(&accG[0][sub * 4 + 3], r0.w);
    }
    if (r1.x != 0.f || r1.y != 0.f || r1.z != 0.f || r1.w != 0.f) {
        atomicAdd(&accG[1][sub * 4 + 0], r1.x);
        atomicAdd(&accG[1][sub * 4 + 1], r1.y);
        atomicAdd(&accG[1][sub * 4 + 2], r1.z);
        atomicAdd(&accG[1][sub * 4 + 3], r1.w);
    }
    __syncthreads();
    {
        int gi = t >> 7, c = t & 127;
        float v = accG[gi][c];
        if (v != 0.f && g0 + gi < NG) atomicAdd(&gsum[(g0 + gi) * HID + c], v);
    }
}

// ---------------- pool finalize (binary-search counts inline) ----------------
__global__ void pool_final(const int* __restrict__ batch, const float* __restrict__ gsum,
                           float* __restrict__ outG) {
    int g = blockIdx.x, t = threadIdx.x;
    int lo = 0, hi = NN;
    while (lo < hi) { int mid = (lo + hi) >> 1; if (batch[mid] < g) lo = mid + 1; else hi = mid; }
    int s = lo;
    int g1 = g + 1;
    lo = 0; hi = NN;
    while (lo < hi) { int mid = (lo + hi) >> 1; if (batch[mid] < g1) lo = mid + 1; else hi = mid; }
    float cnt = fmaxf((float)(lo - s), 1.f);
    outG[g * HID + t] = gsum[g * HID + t] / cnt;
}

extern "C" void kernel_launch(void* const* d_in, const int* in_sizes, int n_in,
                              void* d_out, int out_size, void* d_ws, size_t ws_size,
                              hipStream_t stream) {
    const float* x = (const float*)d_in[0];
    const int* ei = (const int*)d_in[1];
    const int* batch = (const int*)d_in[2];
    const float* W1 = (const float*)d_in[3];
    const float* b1 = (const float*)d_in[4];
    const float* W2 = (const float*)d_in[5];
    const float* b2 = (const float*)d_in[6];
    const float* gamma = (const float*)d_in[7];
    const float* beta = (const float*)d_in[8];
    float* out = (float*)d_out;
    float* outG = out + (size_t)NN * HID;

    // workspace layout
    unsigned short* H0 = (unsigned short*)d_ws;                    // NN*HID bf16 (ping)
    unsigned short* H1 = H0 + (size_t)NN * HID;                    // NN*HID bf16 (pong)
    unsigned short* PB = H1 + (size_t)NN * HID;                    // 25.6MB scratch (pairs, CSR build only)
    int* col = (int*)(PB + (size_t)NN * HID);                      // NE
    int* rowptr = col + NE;                                        // 100004 reserved
    int* ebase = rowptr + 100004;                                  // 512
    int* bcursor = ebase + 512;                                    // 512 (zero region start)
    float* statsP = (float*)(bcursor + 512);                       // 3 * 32 * 256
    float* gsum = statsP + 3 * SBANK * 256;                        // 8192 (zero region end)
    unsigned short* Wp = (unsigned short*)(gsum + 8192);           // 6 x 16384 ushorts
    int* pairs = (int*)PB;                                         // NBUCK*BCAP ints = 12.8MB <= 25.6MB

    const int* srcv = ei;
    const int* dstv = ei + NE;

    hipMemsetAsync(bcursor, 0, (512 + 3 * SBANK * 256 + 8192) * sizeof(int), stream);

    // bucketed CSR build
    pair_scatter<<<NSB, 1024, 0, stream>>>(srcv, dstv, bcursor, pairs);
    bucket_scan<<<1, 512, 0, stream>>>(bcursor, ebase, rowptr);
    bucket_build<<<NBUCK, 256, 0, stream>>>(pairs, bcursor, ebase, rowptr, col);

    // pack weights + convert x to bf16 (single launch)
    prep<<<48 + NN * 16 / 256, 256, 0, stream>>>(x, H0, W1, W2, Wp);

    const int nmlp = (NN + 63) / 64;
    unsigned short* bufs[2] = {H0, H1};
    for (int l = 0; l < 3; ++l) {
        unsigned short* hin = bufs[l & 1];
        unsigned short* hout = bufs[(l + 1) & 1];
        float* sp = statsP + (size_t)l * SBANK * 256;
        mlp_v10<<<nmlp, 512, 0, stream>>>(hin, rowptr, col,
                                          Wp + (size_t)(2 * l) * 16384, b1 + l * HID,
                                          Wp + (size_t)(2 * l + 1) * 16384, b2 + l * HID,
                                          hout, sp);
        if (l < 2)
            bn_relu_bf<<<2048, 256, 0, stream>>>(hout, sp, gamma + l * HID, beta + l * HID);
    }

    // fused final BN+ReLU + pooling (block-local BN finalize)
    bn_pool<<<NN / 32, 256, 0, stream>>>(H1, statsP + 2 * SBANK * 256, gamma + 2 * HID, beta + 2 * HID,
                                         batch, out, gsum);
    pool_final<<<NG, 128, 0, stream>>>(batch, gsum, outG);
}